// Round 2
// baseline (994.787 us; speedup 1.0000x reference)
//
#include <hip/hip_runtime.h>
#include <stdint.h>

typedef __attribute__((ext_vector_type(4))) float f32x4;

// ---------------- CSR build ----------------

__global__ void k_hist(const int* __restrict__ dst, int* __restrict__ deg, int E) {
    int e = blockIdx.x * 256 + threadIdx.x;
    if (e < E) atomicAdd(deg + dst[e], 1);
}

// chunk = 2048 (256 threads x 8). In-place: deg -> within-chunk exclusive prefix.
__global__ void k_scan1(int* __restrict__ buf, int* __restrict__ chunkSum, int N) {
    const int t = threadIdx.x;
    const int base = blockIdx.x * 2048 + t * 8;
    int v[8];
    int s = 0;
#pragma unroll
    for (int i = 0; i < 8; i++) {
        int idx = base + i;
        v[i] = (idx < N) ? buf[idx] : 0;
        s += v[i];
    }
    __shared__ int sh[256];
    sh[t] = s;
    __syncthreads();
    for (int off = 1; off < 256; off <<= 1) {
        int add = (t >= off) ? sh[t - off] : 0;
        __syncthreads();
        sh[t] += add;
        __syncthreads();
    }
    int excl = sh[t] - s;
    int run = excl;
#pragma unroll
    for (int i = 0; i < 8; i++) {
        int idx = base + i;
        if (idx < N) buf[idx] = run;
        run += v[i];
    }
    if (t == 255) chunkSum[blockIdx.x] = sh[255];
}

__global__ void k_scan2(const int* __restrict__ chunkSum, int* __restrict__ chunkOff,
                        int nch, int* __restrict__ rowptrN) {
    if (threadIdx.x == 0 && blockIdx.x == 0) {
        int run = 0;
        for (int i = 0; i < nch; i++) { chunkOff[i] = run; run += chunkSum[i]; }
        *rowptrN = run;
    }
}

__global__ void k_scan3(int* __restrict__ rowptr, const int* __restrict__ chunkOff,
                        int* __restrict__ cursor, int N) {
    int i = blockIdx.x * 256 + threadIdx.x;
    if (i < N) {
        int v = rowptr[i] + chunkOff[i >> 11];
        rowptr[i] = v;
        cursor[i] = v;
    }
}

__global__ void k_fill(const int* __restrict__ src, const int* __restrict__ dst,
                       int* __restrict__ cursor, int* __restrict__ ssrc, int E) {
    int e = blockIdx.x * 256 + threadIdx.x;
    if (e < E) {
        int d = dst[e];
        int pos = atomicAdd(cursor + d, 1);
        ssrc[pos] = src[e];
    }
}

// ---------------- fused dual GEMM (fp32 vector ALU) ----------------
// Cl = A@Wl ; Cr = A@Wr + bias.  A:[M,K] row-major, W:[K,NCOL] row-major.
// Block: 64 rows x NCOL cols, 256 threads, per-thread TMxTN register tile.

template <int K, int NCOL>
__global__ __launch_bounds__(256) void k_gemm2(const float* __restrict__ A,
                                               const float* __restrict__ Wl,
                                               const float* __restrict__ Wr,
                                               const float* __restrict__ bias,
                                               float* __restrict__ Cl,
                                               float* __restrict__ Cr, int M) {
    constexpr int BM = 64, BK = 32, TN = 8;
    constexpr int NCG = NCOL / TN;           // col groups: 16 (NCOL=128) / 8 (NCOL=64)
    constexpr int TM = BM / (256 / NCG);     // 4 / 2
    __shared__ float As[BK][BM + 1];
    __shared__ float Wls[BK][NCOL];
    __shared__ float Wrs[BK][NCOL];

    const int tid = threadIdx.x;
    const int tx = tid % NCG;
    const int ty = tid / NCG;
    const int m0 = blockIdx.x * BM;

    float accl[TM][TN], accr[TM][TN];
#pragma unroll
    for (int i = 0; i < TM; i++)
#pragma unroll
        for (int j = 0; j < TN; j++) { accl[i][j] = 0.f; accr[i][j] = 0.f; }

    for (int k0 = 0; k0 < K; k0 += BK) {
        // stage A tile (64 x 32), transposed into As[k][m]
        {
            const int lr = tid >> 3;
            const int lk = (tid & 7) * 4;
#pragma unroll
            for (int half = 0; half < 2; half++) {
                int mloc = lr + half * 32;
                int m = m0 + mloc;
                f32x4 v = {0.f, 0.f, 0.f, 0.f};
                if (m < M) v = *(const f32x4*)(A + (size_t)m * K + k0 + lk);
                As[lk + 0][mloc] = v[0];
                As[lk + 1][mloc] = v[1];
                As[lk + 2][mloc] = v[2];
                As[lk + 3][mloc] = v[3];
            }
        }
        // stage both W tiles (32 x NCOL)
        {
            constexpr int WNG = NCOL / 4;
            constexpr int KS = 256 / WNG;
            const int wn = (tid % WNG) * 4;
            const int wk0 = tid / WNG;
#pragma unroll
            for (int kk = 0; kk < BK; kk += KS) {
                int k = wk0 + kk;
                *(f32x4*)&Wls[k][wn] = *(const f32x4*)(Wl + (size_t)(k0 + k) * NCOL + wn);
                *(f32x4*)&Wrs[k][wn] = *(const f32x4*)(Wr + (size_t)(k0 + k) * NCOL + wn);
            }
        }
        __syncthreads();

#pragma unroll 4
        for (int k = 0; k < BK; k++) {
            float a[TM];
#pragma unroll
            for (int i = 0; i < TM; i++) a[i] = As[k][ty * TM + i];
            float wl[TN], wr[TN];
#pragma unroll
            for (int j = 0; j < TN; j++) {
                wl[j] = Wls[k][tx * TN + j];
                wr[j] = Wrs[k][tx * TN + j];
            }
#pragma unroll
            for (int i = 0; i < TM; i++)
#pragma unroll
                for (int j = 0; j < TN; j++) {
                    accl[i][j] = fmaf(a[i], wl[j], accl[i][j]);
                    accr[i][j] = fmaf(a[i], wr[j], accr[i][j]);
                }
        }
        __syncthreads();
    }

    float bv[TN];
#pragma unroll
    for (int j = 0; j < TN; j++) bv[j] = bias[tx * TN + j];

#pragma unroll
    for (int i = 0; i < TM; i++) {
        int row = m0 + ty * TM + i;
        if (row < M) {
#pragma unroll
            for (int j = 0; j < TN; j += 4) {
                f32x4 vl = {accl[i][j], accl[i][j + 1], accl[i][j + 2], accl[i][j + 3]};
                f32x4 vr = {accr[i][j] + bv[j], accr[i][j + 1] + bv[j + 1],
                            accr[i][j + 2] + bv[j + 2], accr[i][j + 3] + bv[j + 3]};
                *(f32x4*)(Cl + (size_t)row * NCOL + tx * TN + j) = vl;
                *(f32x4*)(Cr + (size_t)row * NCOL + tx * TN + j) = vr;
            }
        }
    }
}

// ---------------- aggregation ----------------
// res = mean_{s in N(n)} xl[s] + xrb[n]   (bias pre-folded into xrb)
// MODE 0: outA = relu(res)                (layer 0 -> h0)
// MODE 1: outA = res, outB = relu(res)    (layer 1 -> out1, g)
// MODE 2: outA = res                      (layer 2 -> x_final)

template <int COUT, int MODE>
__global__ __launch_bounds__(256) void k_agg(const f32x4* __restrict__ xl,
                                             const f32x4* __restrict__ xrb,
                                             const int* __restrict__ rowptr,
                                             const int* __restrict__ ssrc,
                                             f32x4* __restrict__ outA,
                                             f32x4* __restrict__ outB, int N) {
    constexpr int C4 = COUT / 4;           // lanes per node
    constexpr int NPB = 256 / C4;
    const int tid = threadIdx.x;
    const int c4 = tid % C4;
    const int n = blockIdx.x * NPB + tid / C4;
    if (n >= N) return;

    const int rp0 = rowptr[n];
    const int rp1 = rowptr[n + 1];
    f32x4 acc = {0.f, 0.f, 0.f, 0.f};
    int e = rp0;
    for (; e + 1 < rp1; e += 2) {
        int s0 = ssrc[e];
        int s1 = ssrc[e + 1];
        f32x4 v0 = xl[(size_t)s0 * C4 + c4];
        f32x4 v1 = xl[(size_t)s1 * C4 + c4];
        acc += v0;
        acc += v1;
    }
    if (e < rp1) acc += xl[(size_t)ssrc[e] * C4 + c4];

    const int deg = rp1 - rp0;
    const float scale = 1.0f / (float)(deg > 1 ? deg : 1);
    f32x4 res = acc * scale + xrb[(size_t)n * C4 + c4];

    if (MODE == 0) {
        f32x4 z = {res[0] > 0.f ? res[0] : 0.f, res[1] > 0.f ? res[1] : 0.f,
                   res[2] > 0.f ? res[2] : 0.f, res[3] > 0.f ? res[3] : 0.f};
        outA[(size_t)n * C4 + c4] = z;
    } else if (MODE == 1) {
        outA[(size_t)n * C4 + c4] = res;
        f32x4 z = {res[0] > 0.f ? res[0] : 0.f, res[1] > 0.f ? res[1] : 0.f,
                   res[2] > 0.f ? res[2] : 0.f, res[3] > 0.f ? res[3] : 0.f};
        outB[(size_t)n * C4 + c4] = z;
    } else {
        outA[(size_t)n * C4 + c4] = res;
    }
}

// ---------------- launch ----------------

extern "C" void kernel_launch(void* const* d_in, const int* in_sizes, int n_in,
                              void* d_out, int out_size, void* d_ws, size_t ws_size,
                              hipStream_t stream) {
    const float* x   = (const float*)d_in[0];
    const int*   ei  = (const int*)d_in[1];
    const float* Wl0 = (const float*)d_in[2];
    const float* Wr0 = (const float*)d_in[3];
    const float* b0  = (const float*)d_in[4];
    const float* Wl1 = (const float*)d_in[5];
    const float* Wr1 = (const float*)d_in[6];
    const float* b1  = (const float*)d_in[7];
    const float* Wl2 = (const float*)d_in[8];
    const float* Wr2 = (const float*)d_in[9];
    const float* b2  = (const float*)d_in[10];

    const int N = in_sizes[0] / 256;   // 100000
    const int E = in_sizes[1] / 2;     // 1600000
    const int* src = ei;
    const int* dst = ei + E;

    // workspace carve (256B aligned)
    char* p = (char*)d_ws;
    auto alloc = [&](size_t bytes) -> void* {
        void* r = (void*)p;
        p += (bytes + 255) & ~(size_t)255;
        return r;
    };
    int*   rowptr   = (int*)alloc((size_t)(N + 1) * 4);  // deg before scan
    int*   cursor   = (int*)alloc((size_t)N * 4);
    int*   chunkSum = (int*)alloc(64 * 4);
    int*   chunkOff = (int*)alloc(64 * 4);
    int*   ssrc     = (int*)alloc((size_t)E * 4);
    float* xl       = (float*)alloc((size_t)N * 128 * 4);
    float* xr       = (float*)alloc((size_t)N * 128 * 4);
    float* h0       = (float*)alloc((size_t)N * 128 * 4);

    float* out = (float*)d_out;
    float* x_final = out;                      // N*64
    float* out1    = out + (size_t)N * 64;     // N*128
    float* g       = out + (size_t)N * 192;    // N*128

    // ---- CSR build ----
    hipMemsetAsync(rowptr, 0, (size_t)(N + 1) * 4, stream);
    k_hist<<<(E + 255) / 256, 256, 0, stream>>>(dst, rowptr, E);
    int nch = (N + 2047) / 2048;
    k_scan1<<<nch, 256, 0, stream>>>(rowptr, chunkSum, N);
    k_scan2<<<1, 64, 0, stream>>>(chunkSum, chunkOff, nch, rowptr + N);
    k_scan3<<<(N + 255) / 256, 256, 0, stream>>>(rowptr, chunkOff, cursor, N);
    k_fill<<<(E + 255) / 256, 256, 0, stream>>>(src, dst, cursor, ssrc, E);

    const int gemmGrid = (N + 63) / 64;

    // ---- layer 0: h0 = relu(mean_agg(x@Wl0) + x@Wr0 + b0) ----
    k_gemm2<256, 128><<<gemmGrid, 256, 0, stream>>>(x, Wl0, Wr0, b0, xl, xr, N);
    k_agg<128, 0><<<(N + 7) / 8, 256, 0, stream>>>((const f32x4*)xl, (const f32x4*)xr,
                                                   rowptr, ssrc, (f32x4*)h0, nullptr, N);

    // ---- layer 1: out1 = mean_agg(h0@Wl1) + h0@Wr1 + b1 ; g = relu(out1) ----
    k_gemm2<128, 128><<<gemmGrid, 256, 0, stream>>>(h0, Wl1, Wr1, b1, xl, xr, N);
    k_agg<128, 1><<<(N + 7) / 8, 256, 0, stream>>>((const f32x4*)xl, (const f32x4*)xr,
                                                   rowptr, ssrc, (f32x4*)out1, (f32x4*)g, N);

    // ---- layer 2: x_final = mean_agg(g@Wl2) + g@Wr2 + b2 ----
    k_gemm2<128, 64><<<gemmGrid, 256, 0, stream>>>(g, Wl2, Wr2, b2, xl, xr, N);
    k_agg<64, 2><<<(N + 15) / 16, 256, 0, stream>>>((const f32x4*)xl, (const f32x4*)xr,
                                                    rowptr, ssrc, (f32x4*)x_final, nullptr, N);
}

// Round 3
// 918.121 us; speedup vs baseline: 1.0835x; 1.0835x over previous
//
#include <hip/hip_runtime.h>
#include <stdint.h>

typedef __attribute__((ext_vector_type(4))) float f32x4;
typedef __attribute__((ext_vector_type(4))) uint32_t u32x4;
typedef unsigned short u16;

__device__ inline u16 f2bf(float f) {
    union { float f; uint32_t u; } c; c.f = f;
    uint32_t u = c.u;
    return (u16)((u + 0x7fffu + ((u >> 16) & 1u)) >> 16);
}

// ---------------- CSR build ----------------

__global__ void k_hist(const int* __restrict__ dst, int* __restrict__ deg, int E) {
    int e = blockIdx.x * 256 + threadIdx.x;
    if (e < E) atomicAdd(deg + dst[e], 1);
}

// chunk = 2048 (256 threads x 8). In-place: deg -> within-chunk exclusive prefix.
__global__ void k_scan1(int* __restrict__ buf, int* __restrict__ chunkSum, int N) {
    const int t = threadIdx.x;
    const int base = blockIdx.x * 2048 + t * 8;
    int v[8];
    int s = 0;
#pragma unroll
    for (int i = 0; i < 8; i++) {
        int idx = base + i;
        v[i] = (idx < N) ? buf[idx] : 0;
        s += v[i];
    }
    __shared__ int sh[256];
    sh[t] = s;
    __syncthreads();
    for (int off = 1; off < 256; off <<= 1) {
        int add = (t >= off) ? sh[t - off] : 0;
        __syncthreads();
        sh[t] += add;
        __syncthreads();
    }
    int excl = sh[t] - s;
    int run = excl;
#pragma unroll
    for (int i = 0; i < 8; i++) {
        int idx = base + i;
        if (idx < N) buf[idx] = run;
        run += v[i];
    }
    if (t == 255) chunkSum[blockIdx.x] = sh[255];
}

__global__ void k_scan2(const int* __restrict__ chunkSum, int* __restrict__ chunkOff,
                        int nch, int* __restrict__ rowptrN) {
    if (threadIdx.x == 0 && blockIdx.x == 0) {
        int run = 0;
        for (int i = 0; i < nch; i++) { chunkOff[i] = run; run += chunkSum[i]; }
        *rowptrN = run;
    }
}

__global__ void k_scan3(int* __restrict__ rowptr, const int* __restrict__ chunkOff,
                        int* __restrict__ cursor, int N) {
    int i = blockIdx.x * 256 + threadIdx.x;
    if (i < N) {
        int v = rowptr[i] + chunkOff[i >> 11];
        rowptr[i] = v;
        cursor[i] = v;
    }
}

__global__ void k_fill(const int* __restrict__ src, const int* __restrict__ dst,
                       int* __restrict__ cursor, int* __restrict__ ssrc, int E) {
    int e = blockIdx.x * 256 + threadIdx.x;
    if (e < E) {
        int d = dst[e];
        int pos = atomicAdd(cursor + d, 1);
        ssrc[pos] = src[e];
    }
}

// ---------------- fused dual GEMM (fp32 vector ALU) ----------------
// Clb = bf16(A@Wl) ; Cr = A@Wr + bias.  A:[M,K] row-major, W:[K,NCOL] row-major.
// Block: 64 rows x NCOL cols, 256 threads, per-thread TM x TN register tile.
// Thread tx owns columns {tx, tx+NCG, tx+2*NCG, ...} -> LDS W reads are 16
// consecutive floats across the 16 tx-lanes of a wave => bank-conflict-free.

template <int K, int NCOL>
__global__ __launch_bounds__(256) void k_gemm2(const float* __restrict__ A,
                                               const float* __restrict__ Wl,
                                               const float* __restrict__ Wr,
                                               const float* __restrict__ bias,
                                               u16* __restrict__ Clb,
                                               float* __restrict__ Cr, int M) {
    constexpr int BM = 64, BK = 32, TN = 8;
    constexpr int NCG = NCOL / TN;           // col groups: 16 (NCOL=128) / 8 (NCOL=64)
    constexpr int TM = BM / (256 / NCG);     // 4 / 2
    __shared__ float As[BK][BM + 1];
    __shared__ float Wls[BK][NCOL];
    __shared__ float Wrs[BK][NCOL];

    const int tid = threadIdx.x;
    const int tx = tid % NCG;
    const int ty = tid / NCG;
    const int m0 = blockIdx.x * BM;

    float accl[TM][TN], accr[TM][TN];
#pragma unroll
    for (int i = 0; i < TM; i++)
#pragma unroll
        for (int j = 0; j < TN; j++) { accl[i][j] = 0.f; accr[i][j] = 0.f; }

    for (int k0 = 0; k0 < K; k0 += BK) {
        // stage A tile (64 x 32), transposed into As[k][m]
        {
            const int lr = tid >> 3;
            const int lk = (tid & 7) * 4;
#pragma unroll
            for (int half = 0; half < 2; half++) {
                int mloc = lr + half * 32;
                int m = m0 + mloc;
                f32x4 v = {0.f, 0.f, 0.f, 0.f};
                if (m < M) v = *(const f32x4*)(A + (size_t)m * K + k0 + lk);
                As[lk + 0][mloc] = v[0];
                As[lk + 1][mloc] = v[1];
                As[lk + 2][mloc] = v[2];
                As[lk + 3][mloc] = v[3];
            }
        }
        // stage both W tiles (32 x NCOL)
        {
            constexpr int WNG = NCOL / 4;
            constexpr int KS = 256 / WNG;
            const int wn = (tid % WNG) * 4;
            const int wk0 = tid / WNG;
#pragma unroll
            for (int kk = 0; kk < BK; kk += KS) {
                int k = wk0 + kk;
                *(f32x4*)&Wls[k][wn] = *(const f32x4*)(Wl + (size_t)(k0 + k) * NCOL + wn);
                *(f32x4*)&Wrs[k][wn] = *(const f32x4*)(Wr + (size_t)(k0 + k) * NCOL + wn);
            }
        }
        __syncthreads();

#pragma unroll 4
        for (int k = 0; k < BK; k++) {
            float a[TM];
#pragma unroll
            for (int i = 0; i < TM; i++) a[i] = As[k][ty * TM + i];
            float wl[TN], wr[TN];
#pragma unroll
            for (int j = 0; j < TN; j++) {
                wl[j] = Wls[k][j * NCG + tx];
                wr[j] = Wrs[k][j * NCG + tx];
            }
#pragma unroll
            for (int i = 0; i < TM; i++)
#pragma unroll
                for (int j = 0; j < TN; j++) {
                    accl[i][j] = fmaf(a[i], wl[j], accl[i][j]);
                    accr[i][j] = fmaf(a[i], wr[j], accr[i][j]);
                }
        }
        __syncthreads();
    }

    float bv[TN];
#pragma unroll
    for (int j = 0; j < TN; j++) bv[j] = bias[j * NCG + tx];

#pragma unroll
    for (int i = 0; i < TM; i++) {
        int row = m0 + ty * TM + i;
        if (row < M) {
#pragma unroll
            for (int j = 0; j < TN; j++) {
                int col = j * NCG + tx;
                Cr[(size_t)row * NCOL + col] = accr[i][j] + bv[j];
                Clb[(size_t)row * NCOL + col] = f2bf(accl[i][j]);
            }
        }
    }
}

// ---------------- aggregation ----------------
// res = mean_{s in N(n)} bf16(xl)[s] + xrb[n]   (bias pre-folded into xrb)
// MODE 0: outA = relu(res)                (layer 0 -> h0)
// MODE 1: outA = res, outB = relu(res)    (layer 1 -> out1, g)
// MODE 2: outA = res                      (layer 2 -> x_final)

__device__ inline void upadd(uint32_t u, float& lo, float& hi) {
    union { uint32_t u; float f; } a, b;
    a.u = u << 16;
    b.u = u & 0xffff0000u;
    lo += a.f;
    hi += b.f;
}

template <int COUT, int MODE>
__global__ __launch_bounds__(256) void k_agg(const u32x4* __restrict__ xlb,
                                             const float* __restrict__ xrb,
                                             const int* __restrict__ rowptr,
                                             const int* __restrict__ ssrc,
                                             float* __restrict__ outA,
                                             float* __restrict__ outB, int N) {
    constexpr int LPN = COUT / 8;          // lanes per node (8 channels / lane)
    constexpr int NPB = 256 / LPN;
    const int tid = threadIdx.x;
    const int c = tid % LPN;
    const int n = blockIdx.x * NPB + tid / LPN;
    if (n >= N) return;

    const int rp0 = rowptr[n];
    const int rp1 = rowptr[n + 1];
    float acc[8] = {0.f, 0.f, 0.f, 0.f, 0.f, 0.f, 0.f, 0.f};

    int e = rp0;
    for (; e + 1 < rp1; e += 2) {
        int s0 = ssrc[e];
        int s1 = ssrc[e + 1];
        u32x4 v0 = xlb[(size_t)s0 * LPN + c];
        u32x4 v1 = xlb[(size_t)s1 * LPN + c];
#pragma unroll
        for (int q = 0; q < 4; q++) upadd(v0[q], acc[q * 2], acc[q * 2 + 1]);
#pragma unroll
        for (int q = 0; q < 4; q++) upadd(v1[q], acc[q * 2], acc[q * 2 + 1]);
    }
    if (e < rp1) {
        u32x4 v = xlb[(size_t)ssrc[e] * LPN + c];
#pragma unroll
        for (int q = 0; q < 4; q++) upadd(v[q], acc[q * 2], acc[q * 2 + 1]);
    }

    const int deg = rp1 - rp0;
    const float scale = 1.0f / (float)(deg > 1 ? deg : 1);
    const float* xr = xrb + (size_t)n * COUT + c * 8;
    f32x4 x0 = *(const f32x4*)(xr);
    f32x4 x1 = *(const f32x4*)(xr + 4);
    f32x4 r0 = {acc[0] * scale + x0[0], acc[1] * scale + x0[1],
                acc[2] * scale + x0[2], acc[3] * scale + x0[3]};
    f32x4 r1 = {acc[4] * scale + x1[0], acc[5] * scale + x1[1],
                acc[6] * scale + x1[2], acc[7] * scale + x1[3]};

    float* pA = outA + (size_t)n * COUT + c * 8;
    if (MODE == 0) {
        f32x4 z0 = {r0[0] > 0.f ? r0[0] : 0.f, r0[1] > 0.f ? r0[1] : 0.f,
                    r0[2] > 0.f ? r0[2] : 0.f, r0[3] > 0.f ? r0[3] : 0.f};
        f32x4 z1 = {r1[0] > 0.f ? r1[0] : 0.f, r1[1] > 0.f ? r1[1] : 0.f,
                    r1[2] > 0.f ? r1[2] : 0.f, r1[3] > 0.f ? r1[3] : 0.f};
        *(f32x4*)(pA) = z0;
        *(f32x4*)(pA + 4) = z1;
    } else if (MODE == 1) {
        *(f32x4*)(pA) = r0;
        *(f32x4*)(pA + 4) = r1;
        f32x4 z0 = {r0[0] > 0.f ? r0[0] : 0.f, r0[1] > 0.f ? r0[1] : 0.f,
                    r0[2] > 0.f ? r0[2] : 0.f, r0[3] > 0.f ? r0[3] : 0.f};
        f32x4 z1 = {r1[0] > 0.f ? r1[0] : 0.f, r1[1] > 0.f ? r1[1] : 0.f,
                    r1[2] > 0.f ? r1[2] : 0.f, r1[3] > 0.f ? r1[3] : 0.f};
        float* pB = outB + (size_t)n * COUT + c * 8;
        *(f32x4*)(pB) = z0;
        *(f32x4*)(pB + 4) = z1;
    } else {
        *(f32x4*)(pA) = r0;
        *(f32x4*)(pA + 4) = r1;
    }
}

// ---------------- launch ----------------

extern "C" void kernel_launch(void* const* d_in, const int* in_sizes, int n_in,
                              void* d_out, int out_size, void* d_ws, size_t ws_size,
                              hipStream_t stream) {
    const float* x   = (const float*)d_in[0];
    const int*   ei  = (const int*)d_in[1];
    const float* Wl0 = (const float*)d_in[2];
    const float* Wr0 = (const float*)d_in[3];
    const float* b0  = (const float*)d_in[4];
    const float* Wl1 = (const float*)d_in[5];
    const float* Wr1 = (const float*)d_in[6];
    const float* b1  = (const float*)d_in[7];
    const float* Wl2 = (const float*)d_in[8];
    const float* Wr2 = (const float*)d_in[9];
    const float* b2  = (const float*)d_in[10];

    const int N = in_sizes[0] / 256;   // 100000
    const int E = in_sizes[1] / 2;     // 1600000
    const int* src = ei;
    const int* dst = ei + E;

    // workspace carve (256B aligned)
    char* p = (char*)d_ws;
    auto alloc = [&](size_t bytes) -> void* {
        void* r = (void*)p;
        p += (bytes + 255) & ~(size_t)255;
        return r;
    };
    int*   rowptr   = (int*)alloc((size_t)(N + 1) * 4);  // deg before scan
    int*   cursor   = (int*)alloc((size_t)N * 4);
    int*   chunkSum = (int*)alloc(64 * 4);
    int*   chunkOff = (int*)alloc(64 * 4);
    int*   ssrc     = (int*)alloc((size_t)E * 4);
    u16*   xlb      = (u16*)alloc((size_t)N * 128 * 2);   // bf16 l-path projection
    float* xr       = (float*)alloc((size_t)N * 128 * 4);
    float* h0       = (float*)alloc((size_t)N * 128 * 4);

    float* out = (float*)d_out;
    float* x_final = out;                      // N*64
    float* out1    = out + (size_t)N * 64;     // N*128
    float* g       = out + (size_t)N * 192;    // N*128

    // ---- CSR build ----
    hipMemsetAsync(rowptr, 0, (size_t)(N + 1) * 4, stream);
    k_hist<<<(E + 255) / 256, 256, 0, stream>>>(dst, rowptr, E);
    int nch = (N + 2047) / 2048;
    k_scan1<<<nch, 256, 0, stream>>>(rowptr, chunkSum, N);
    k_scan2<<<1, 64, 0, stream>>>(chunkSum, chunkOff, nch, rowptr + N);
    k_scan3<<<(N + 255) / 256, 256, 0, stream>>>(rowptr, chunkOff, cursor, N);
    k_fill<<<(E + 255) / 256, 256, 0, stream>>>(src, dst, cursor, ssrc, E);

    const int gemmGrid = (N + 63) / 64;

    // ---- layer 0: h0 = relu(mean_agg(x@Wl0) + x@Wr0 + b0) ----
    k_gemm2<256, 128><<<gemmGrid, 256, 0, stream>>>(x, Wl0, Wr0, b0, xlb, xr, N);
    k_agg<128, 0><<<(N + 15) / 16, 256, 0, stream>>>((const u32x4*)xlb, xr,
                                                     rowptr, ssrc, h0, nullptr, N);

    // ---- layer 1: out1 = mean_agg(h0@Wl1) + h0@Wr1 + b1 ; g = relu(out1) ----
    k_gemm2<128, 128><<<gemmGrid, 256, 0, stream>>>(h0, Wl1, Wr1, b1, xlb, xr, N);
    k_agg<128, 1><<<(N + 15) / 16, 256, 0, stream>>>((const u32x4*)xlb, xr,
                                                     rowptr, ssrc, out1, g, N);

    // ---- layer 2: x_final = mean_agg(g@Wl2) + g@Wr2 + b2 ----
    k_gemm2<128, 64><<<gemmGrid, 256, 0, stream>>>(g, Wl2, Wr2, b2, xlb, xr, N);
    k_agg<64, 2><<<(N + 31) / 32, 256, 0, stream>>>((const u32x4*)xlb, xr,
                                                    rowptr, ssrc, x_final, nullptr, N);
}

// Round 4
// 758.798 us; speedup vs baseline: 1.3110x; 1.2100x over previous
//
#include <hip/hip_runtime.h>
#include <stdint.h>

typedef __attribute__((ext_vector_type(4))) float f32x4;
typedef _Float16 half8 __attribute__((ext_vector_type(8)));

// ---------------- CSR build ----------------

__global__ void k_hist(const int* __restrict__ dst, int* __restrict__ deg, int E) {
    int e = blockIdx.x * 256 + threadIdx.x;
    if (e < E) atomicAdd(deg + dst[e], 1);
}

__global__ void k_scan1(int* __restrict__ buf, int* __restrict__ chunkSum, int N) {
    const int t = threadIdx.x;
    const int base = blockIdx.x * 2048 + t * 8;
    int v[8];
    int s = 0;
#pragma unroll
    for (int i = 0; i < 8; i++) {
        int idx = base + i;
        v[i] = (idx < N) ? buf[idx] : 0;
        s += v[i];
    }
    __shared__ int sh[256];
    sh[t] = s;
    __syncthreads();
    for (int off = 1; off < 256; off <<= 1) {
        int add = (t >= off) ? sh[t - off] : 0;
        __syncthreads();
        sh[t] += add;
        __syncthreads();
    }
    int excl = sh[t] - s;
    int run = excl;
#pragma unroll
    for (int i = 0; i < 8; i++) {
        int idx = base + i;
        if (idx < N) buf[idx] = run;
        run += v[i];
    }
    if (t == 255) chunkSum[blockIdx.x] = sh[255];
}

__global__ void k_scan2(const int* __restrict__ chunkSum, int* __restrict__ chunkOff,
                        int nch, int* __restrict__ rowptrN) {
    if (threadIdx.x == 0 && blockIdx.x == 0) {
        int run = 0;
        for (int i = 0; i < nch; i++) { chunkOff[i] = run; run += chunkSum[i]; }
        *rowptrN = run;
    }
}

__global__ void k_scan3(int* __restrict__ rowptr, const int* __restrict__ chunkOff,
                        int* __restrict__ cursor, int N) {
    int i = blockIdx.x * 256 + threadIdx.x;
    if (i < N) {
        int v = rowptr[i] + chunkOff[i >> 11];
        rowptr[i] = v;
        cursor[i] = v;
    }
}

__global__ void k_fill(const int* __restrict__ src, const int* __restrict__ dst,
                       int* __restrict__ cursor, int* __restrict__ ssrc, int E) {
    int e = blockIdx.x * 256 + threadIdx.x;
    if (e < E) {
        int d = dst[e];
        int pos = atomicAdd(cursor + d, 1);
        ssrc[pos] = src[e];
    }
}

// ---------------- weight prep: Wt[n][k] = f16( n<NCOL ? Wl[k][n] : Wr[k][n-NCOL] ) ----------------

template <int K, int NCOLT>
__global__ void k_wprep(const float* __restrict__ Wl, const float* __restrict__ Wr,
                        _Float16* __restrict__ Wt) {
    constexpr int NCOL = NCOLT / 2;
    int i = blockIdx.x * 256 + threadIdx.x;
    if (i < K * NCOLT) {
        int n = i / K, k = i - n * K;
        float v = (n < NCOL) ? Wl[(size_t)k * NCOL + n] : Wr[(size_t)k * NCOL + (n - NCOL)];
        Wt[i] = (_Float16)v;
    }
}

// ---------------- MFMA GEMM: [Cl|Cr] = A @ [Wl|Wr] (f16 in, fp32 acc, f16 out) ----------------
// Block: 256 thr = 4 waves, 64 rows. Wave w owns cols [w*WC, (w+1)*WC) of NCOLT.
// Verified m97 mapping: A-frag A[m=lane&15][k0+quad*8+j]; B-frag Wt[n=l16+..][k0+quad*8+j];
// D: col=lane&15, row=quad*4+reg.

template <int K, int NCOLT, bool AF32>
__global__ __launch_bounds__(256) void k_gemmM(const void* __restrict__ Av,
                                               const _Float16* __restrict__ Wt,
                                               const float* __restrict__ bias,
                                               _Float16* __restrict__ Cl,
                                               _Float16* __restrict__ Cr, int M) {
    constexpr int NCOL = NCOLT / 2;
    constexpr int WC = NCOLT / 4;   // cols per wave: 64 (NCOLT=256) / 32 (NCOLT=128)
    constexpr int NT = WC / 16;     // col tiles per wave: 4 / 2
    const int tid = threadIdx.x;
    const int lane = tid & 63;
    const int wave = tid >> 6;
    const int quad = lane >> 4;
    const int l16 = lane & 15;
    const int m0 = blockIdx.x * 64;
    const int colbase = wave * WC;

    f32x4 acc[4][NT];
#pragma unroll
    for (int rg = 0; rg < 4; rg++)
#pragma unroll
        for (int t = 0; t < NT; t++) acc[rg][t] = (f32x4){0.f, 0.f, 0.f, 0.f};

#pragma unroll
    for (int k0 = 0; k0 < K; k0 += 32) {
        half8 a[4];
#pragma unroll
        for (int rg = 0; rg < 4; rg++) {
            int m = m0 + rg * 16 + l16;
            if (AF32) {
                f32x4 u0 = {0.f, 0.f, 0.f, 0.f}, u1 = {0.f, 0.f, 0.f, 0.f};
                if (m < M) {
                    const float* ap = (const float*)Av + (size_t)m * K + k0 + quad * 8;
                    u0 = *(const f32x4*)ap;
                    u1 = *(const f32x4*)(ap + 4);
                }
                a[rg] = (half8){(_Float16)u0[0], (_Float16)u0[1], (_Float16)u0[2], (_Float16)u0[3],
                                (_Float16)u1[0], (_Float16)u1[1], (_Float16)u1[2], (_Float16)u1[3]};
            } else {
                half8 az = {0, 0, 0, 0, 0, 0, 0, 0};
                a[rg] = (m < M)
                    ? *(const half8*)((const _Float16*)Av + (size_t)m * K + k0 + quad * 8)
                    : az;
            }
        }
        half8 b[NT];
#pragma unroll
        for (int t = 0; t < NT; t++)
            b[t] = *(const half8*)(Wt + (size_t)(colbase + t * 16 + l16) * K + k0 + quad * 8);
#pragma unroll
        for (int rg = 0; rg < 4; rg++)
#pragma unroll
            for (int t = 0; t < NT; t++)
                acc[rg][t] = __builtin_amdgcn_mfma_f32_16x16x32_f16(a[rg], b[t], acc[rg][t], 0, 0, 0);
    }

    const bool isR = (colbase >= NCOL);
#pragma unroll
    for (int t = 0; t < NT; t++) {
        int col = colbase + t * 16 + l16;
        float bv = isR ? bias[col - NCOL] : 0.f;
        _Float16* dst = isR ? (Cr + (col - NCOL)) : (Cl + col);
#pragma unroll
        for (int rg = 0; rg < 4; rg++) {
#pragma unroll
            for (int r = 0; r < 4; r++) {
                int row = m0 + rg * 16 + quad * 4 + r;
                if (row < M) dst[(size_t)row * NCOL] = (_Float16)(acc[rg][t][r] + bv);
            }
        }
    }
}

// ---------------- aggregation ----------------
// res = mean_{s in N(n)} xl[s] + xr[n]  (bias already folded into xr by GEMM epilogue)
// MODE 0: outH = f16(relu(res))                       (h0)
// MODE 1: outF1 = res, outF2 = relu(res), outH = f16(relu(res))   (out1, g, gb)
// MODE 2: outF1 = res                                 (x_final)
// Lane owns 16 channels (2 x half8). 4-edge unroll => 8 b128 loads in flight.

template <int COUT, int MODE>
__global__ __launch_bounds__(256) void k_agg(const half8* __restrict__ xl,
                                             const half8* __restrict__ xr,
                                             const int* __restrict__ rowptr,
                                             const int* __restrict__ ssrc,
                                             float* __restrict__ outF1,
                                             float* __restrict__ outF2,
                                             _Float16* __restrict__ outH, int N) {
    constexpr int LPN = COUT / 16;       // lanes per node
    constexpr int NPB = 256 / LPN;
    constexpr int C8 = COUT / 8;         // half8s per row
    const int tid = threadIdx.x;
    const int c = tid % LPN;
    const int n = blockIdx.x * NPB + tid / LPN;
    if (n >= N) return;

    const int rp0 = rowptr[n];
    const int rp1 = rowptr[n + 1];
    float acc[16];
#pragma unroll
    for (int i = 0; i < 16; i++) acc[i] = 0.f;

    const size_t cb = (size_t)c * 2;
    int e = rp0;
    for (; e + 3 < rp1; e += 4) {
        int s0 = ssrc[e], s1 = ssrc[e + 1], s2 = ssrc[e + 2], s3 = ssrc[e + 3];
        half8 v0a = xl[(size_t)s0 * C8 + cb], v0b = xl[(size_t)s0 * C8 + cb + 1];
        half8 v1a = xl[(size_t)s1 * C8 + cb], v1b = xl[(size_t)s1 * C8 + cb + 1];
        half8 v2a = xl[(size_t)s2 * C8 + cb], v2b = xl[(size_t)s2 * C8 + cb + 1];
        half8 v3a = xl[(size_t)s3 * C8 + cb], v3b = xl[(size_t)s3 * C8 + cb + 1];
#pragma unroll
        for (int i = 0; i < 8; i++) {
            acc[i] += (float)v0a[i] + (float)v1a[i] + (float)v2a[i] + (float)v3a[i];
            acc[8 + i] += (float)v0b[i] + (float)v1b[i] + (float)v2b[i] + (float)v3b[i];
        }
    }
    for (; e < rp1; e++) {
        int s = ssrc[e];
        half8 va = xl[(size_t)s * C8 + cb], vb = xl[(size_t)s * C8 + cb + 1];
#pragma unroll
        for (int i = 0; i < 8; i++) {
            acc[i] += (float)va[i];
            acc[8 + i] += (float)vb[i];
        }
    }

    const int deg = rp1 - rp0;
    const float scale = 1.0f / (float)(deg > 1 ? deg : 1);
    half8 x0 = xr[(size_t)n * C8 + cb];
    half8 x1 = xr[(size_t)n * C8 + cb + 1];
    float res[16];
#pragma unroll
    for (int i = 0; i < 8; i++) {
        res[i] = acc[i] * scale + (float)x0[i];
        res[8 + i] = acc[8 + i] * scale + (float)x1[i];
    }

    const size_t ob = (size_t)n * COUT + (size_t)c * 16;
    if (MODE == 0) {
        half8 h0v, h1v;
#pragma unroll
        for (int i = 0; i < 8; i++) {
            h0v[i] = (_Float16)(res[i] > 0.f ? res[i] : 0.f);
            h1v[i] = (_Float16)(res[8 + i] > 0.f ? res[8 + i] : 0.f);
        }
        *(half8*)(outH + ob) = h0v;
        *(half8*)(outH + ob + 8) = h1v;
    } else if (MODE == 1) {
#pragma unroll
        for (int q = 0; q < 4; q++) {
            f32x4 v = {res[q * 4], res[q * 4 + 1], res[q * 4 + 2], res[q * 4 + 3]};
            *(f32x4*)(outF1 + ob + q * 4) = v;
            f32x4 z = {v[0] > 0.f ? v[0] : 0.f, v[1] > 0.f ? v[1] : 0.f,
                       v[2] > 0.f ? v[2] : 0.f, v[3] > 0.f ? v[3] : 0.f};
            *(f32x4*)(outF2 + ob + q * 4) = z;
        }
        half8 h0v, h1v;
#pragma unroll
        for (int i = 0; i < 8; i++) {
            h0v[i] = (_Float16)(res[i] > 0.f ? res[i] : 0.f);
            h1v[i] = (_Float16)(res[8 + i] > 0.f ? res[8 + i] : 0.f);
        }
        *(half8*)(outH + ob) = h0v;
        *(half8*)(outH + ob + 8) = h1v;
    } else {
#pragma unroll
        for (int q = 0; q < 4; q++) {
            f32x4 v = {res[q * 4], res[q * 4 + 1], res[q * 4 + 2], res[q * 4 + 3]};
            *(f32x4*)(outF1 + ob + q * 4) = v;
        }
    }
}

// ---------------- launch ----------------

extern "C" void kernel_launch(void* const* d_in, const int* in_sizes, int n_in,
                              void* d_out, int out_size, void* d_ws, size_t ws_size,
                              hipStream_t stream) {
    const float* x   = (const float*)d_in[0];
    const int*   ei  = (const int*)d_in[1];
    const float* Wl0 = (const float*)d_in[2];
    const float* Wr0 = (const float*)d_in[3];
    const float* b0  = (const float*)d_in[4];
    const float* Wl1 = (const float*)d_in[5];
    const float* Wr1 = (const float*)d_in[6];
    const float* b1  = (const float*)d_in[7];
    const float* Wl2 = (const float*)d_in[8];
    const float* Wr2 = (const float*)d_in[9];
    const float* b2  = (const float*)d_in[10];

    const int N = in_sizes[0] / 256;   // 100000
    const int E = in_sizes[1] / 2;     // 1600000
    const int* src = ei;
    const int* dst = ei + E;

    char* p = (char*)d_ws;
    auto alloc = [&](size_t bytes) -> void* {
        void* r = (void*)p;
        p += (bytes + 255) & ~(size_t)255;
        return r;
    };
    int*      rowptr   = (int*)alloc((size_t)(N + 1) * 4);
    int*      cursor   = (int*)alloc((size_t)N * 4);
    int*      chunkSum = (int*)alloc(64 * 4);
    int*      chunkOff = (int*)alloc(64 * 4);
    int*      ssrc     = (int*)alloc((size_t)E * 4);
    _Float16* xl       = (_Float16*)alloc((size_t)N * 128 * 2);
    _Float16* xr       = (_Float16*)alloc((size_t)N * 128 * 2);
    _Float16* h0       = (_Float16*)alloc((size_t)N * 128 * 2);
    _Float16* gb       = (_Float16*)alloc((size_t)N * 128 * 2);
    _Float16* Wt0      = (_Float16*)alloc((size_t)256 * 256 * 2);
    _Float16* Wt1      = (_Float16*)alloc((size_t)256 * 128 * 2);
    _Float16* Wt2      = (_Float16*)alloc((size_t)128 * 128 * 2);

    float* out = (float*)d_out;
    float* x_final = out;                      // N*64
    float* out1    = out + (size_t)N * 64;     // N*128
    float* g       = out + (size_t)N * 192;    // N*128

    // ---- CSR build ----
    hipMemsetAsync(rowptr, 0, (size_t)(N + 1) * 4, stream);
    k_hist<<<(E + 255) / 256, 256, 0, stream>>>(dst, rowptr, E);
    int nch = (N + 2047) / 2048;
    k_scan1<<<nch, 256, 0, stream>>>(rowptr, chunkSum, N);
    k_scan2<<<1, 64, 0, stream>>>(chunkSum, chunkOff, nch, rowptr + N);
    k_scan3<<<(N + 255) / 256, 256, 0, stream>>>(rowptr, chunkOff, cursor, N);
    k_fill<<<(E + 255) / 256, 256, 0, stream>>>(src, dst, cursor, ssrc, E);

    // ---- weight prep ----
    k_wprep<256, 256><<<(256 * 256 + 255) / 256, 256, 0, stream>>>(Wl0, Wr0, Wt0);
    k_wprep<128, 256><<<(128 * 256 + 255) / 256, 256, 0, stream>>>(Wl1, Wr1, Wt1);
    k_wprep<128, 128><<<(128 * 128 + 255) / 256, 256, 0, stream>>>(Wl2, Wr2, Wt2);

    const int gGrid = (N + 63) / 64;

    // ---- layer 0 ----
    k_gemmM<256, 256, true><<<gGrid, 256, 0, stream>>>(x, Wt0, b0, xl, xr, N);
    k_agg<128, 0><<<(N + 31) / 32, 256, 0, stream>>>((const half8*)xl, (const half8*)xr,
                                                     rowptr, ssrc, nullptr, nullptr, h0, N);

    // ---- layer 1 ----
    k_gemmM<128, 256, false><<<gGrid, 256, 0, stream>>>(h0, Wt1, b1, xl, xr, N);
    k_agg<128, 1><<<(N + 31) / 32, 256, 0, stream>>>((const half8*)xl, (const half8*)xr,
                                                     rowptr, ssrc, out1, g, gb, N);

    // ---- layer 2 ----
    k_gemmM<128, 128, false><<<gGrid, 256, 0, stream>>>(gb, Wt2, b2, xl, xr, N);
    k_agg<64, 2><<<(N + 63) / 64, 256, 0, stream>>>((const half8*)xl, (const half8*)xr,
                                                    rowptr, ssrc, x_final, nullptr, nullptr, N);
}